// Round 7
// baseline (435.306 us; speedup 1.0000x reference)
//
#include <hip/hip_runtime.h>

#define Lr 2048
#define Dr 1024
#define Nr 16
#define Gc 64           // chunks along L
#define LC 32           // Lr/Gc
#define NS 16           // d-slices (Dr/64)
#define NT (Gc*NS)      // 1024 tiles
#define CPB 1024        // chains per tile (64 d x 16 n)
#define DN (Dr*Nr)

#define LOG2E 1.442695041f
#define LN2   0.69314718056f
#define SCOPE __HIP_MEMORY_SCOPE_AGENT

typedef float f32x4 __attribute__((ext_vector_type(4)));

__device__ __forceinline__ float exp2_hw(float x){ return __builtin_amdgcn_exp2f(x); }
__device__ __forceinline__ float log2_hw(float x){ return __builtin_amdgcn_logf(x); }
__device__ __forceinline__ float exp_hw(float x) { return exp2_hw(x*LOG2E); }
__device__ __forceinline__ float softplus_fast(float x){
  float t = exp2_hw(-LOG2E*fabsf(x));
  return fmaxf(x, 0.f) + LN2*log2_hw(1.f + t);
}

// z[l] = dot(xs[l,:], WD) + bD; blocks 0..4 also zero flags+ticket (NT+1 ints)
__global__ void k_rowdot(const float* __restrict__ xs, const float* __restrict__ WD,
                         const float* __restrict__ bD, float* __restrict__ z,
                         int* __restrict__ flags){
  if (blockIdx.x < 5){
    int i = blockIdx.x*256 + threadIdx.x;
    if (i < NT+1) flags[i] = 0;
  }
  int l = blockIdx.x;
  const float4* row = (const float4*)(xs + (size_t)l*Dr);
  const float4* w4  = (const float4*)WD;
  int i = threadIdx.x;           // Dr/4 == 256 == blockDim
  float4 a = row[i], b = w4[i];
  float s = fmaf(a.x,b.x, fmaf(a.y,b.y, fmaf(a.z,b.z, a.w*b.w)));
  #pragma unroll
  for (int off = 32; off > 0; off >>= 1) s += __shfl_down(s, off, 64);
  __shared__ float red[4];
  int wid = threadIdx.x >> 6, lane = threadIdx.x & 63;
  if (lane == 0) red[wid] = s;
  __syncthreads();
  if (threadIdx.x == 0) z[l] = red[0] + red[1] + red[2] + red[3] + bD[0];
}

// Fused single-pass chunked scan with decoupled look-back.
// Tile t = (g = t>>4, s = t&15): chunk g (32 l's), d in [s*64, s*64+64), all 16 n.
// Thread: (d_local = tid>>2, n4 = tid&3) -> 4 chains.
// Race-free publication: aggregate payload (aggA/aggB, flag=1) and inclusive
// prefix payload (prefA/prefB, flag=2) live in SEPARATE single-writer arrays;
// each location is immutable once its flag is released.
__global__ __launch_bounds__(256) void k_fused(
    const float* __restrict__ xs, const float* __restrict__ WB,
    const float* __restrict__ bB, const float* __restrict__ WC,
    const float* __restrict__ bC, const float* __restrict__ lnA,
    const float* __restrict__ dparam, const float* __restrict__ z,
    float* __restrict__ aggA, float* __restrict__ aggB,
    float* __restrict__ prefA, float* __restrict__ prefB,
    int* __restrict__ flags, int* __restrict__ ticket,
    float* __restrict__ ys, float* __restrict__ hs){
  __shared__ int sh_tile, sh_flag;
  if (threadIdx.x == 0) sh_tile = atomicAdd(ticket, 1);
  __syncthreads();
  const int tile = sh_tile;
  const int g = tile >> 4, s = tile & (NS-1);
  const int n4 = threadIdx.x & 3, d_local = threadIdx.x >> 2;
  const int d = s*64 + d_local;

  float4 la = *(const float4*)(lnA + d*Nr + n4*4);
  float4 wb = *(const float4*)(WB + n4*4);
  float4 bb = *(const float4*)(bB + n4*4);
  float lav[4] = {la.x,la.y,la.z,la.w};
  float wbv[4] = {wb.x,wb.y,wb.z,wb.w};
  float bbv[4] = {bb.x,bb.y,bb.z,bb.w};
  float ad2[4], p[4], q[4];
  #pragma unroll
  for (int j=0;j<4;j++){
    float a = -exp_hw(lav[j]);
    ad2[j] = a*LOG2E;
    float ia = 1.f/a;
    p[j] = wbv[j]*ia; q[j] = bbv[j]*ia;
  }
  const float dp = dparam[d];
  const int l0 = g*LC;

  // ---- pass A: local chunk aggregate (Ap = prod A, Bc = local scan-B) ----
  float Ap[4] = {1.f,1.f,1.f,1.f}, Bc[4] = {0.f,0.f,0.f,0.f};
  #pragma unroll 2
  for (int i=0;i<LC;i++){
    int l = l0+i;
    float x  = xs[(size_t)l*Dr + d];
    float dl = softplus_fast(dp + z[l]);
    float x2 = x*x;
    #pragma unroll
    for (int j=0;j<4;j++){
      float Ab = exp2_hw(dl*ad2[j]);
      float Bx = (Ab-1.f)*fmaf(x2, p[j], x*q[j]);
      Ap[j] *= Ab;
      Bc[j] = fmaf(Ab, Bc[j], Bx);
    }
  }

  const size_t base = (size_t)tile*CPB + threadIdx.x*4;
  float accA[4] = {1.f,1.f,1.f,1.f}, accB[4] = {0.f,0.f,0.f,0.f};
  if (g > 0){
    // publish aggregate (flag 1)
    #pragma unroll
    for (int j=0;j<4;j++){
      __hip_atomic_store(aggA+base+j, Ap[j], __ATOMIC_RELAXED, SCOPE);
      __hip_atomic_store(aggB+base+j, Bc[j], __ATOMIC_RELAXED, SCOPE);
    }
    __threadfence();
    __syncthreads();
    if (threadIdx.x == 0)
      __hip_atomic_store(flags+tile, 1, __ATOMIC_RELEASE, SCOPE);
    // decoupled look-back over predecessors (same s)
    int tk = tile - NS;
    for (;;){
      __syncthreads();
      if (threadIdx.x == 0){
        int f;
        do {
          f = __hip_atomic_load(flags+tk, __ATOMIC_ACQUIRE, SCOPE);
          if (!f) __builtin_amdgcn_s_sleep(8);
        } while (!f);
        sh_flag = f;
      }
      __syncthreads();
      const int f1 = sh_flag;
      const size_t pb = (size_t)tk*CPB + threadIdx.x*4;
      const float* SA = (f1 == 1) ? aggA : prefA;
      const float* SB = (f1 == 1) ? aggB : prefB;
      float A_[4], B_[4];
      #pragma unroll
      for (int j=0;j<4;j++){
        A_[j] = __hip_atomic_load(SA+pb+j, __ATOMIC_RELAXED, SCOPE);
        B_[j] = __hip_atomic_load(SB+pb+j, __ATOMIC_RELAXED, SCOPE);
      }
      #pragma unroll
      for (int j=0;j<4;j++){
        accB[j] = fmaf(accA[j], B_[j], accB[j]);
        accA[j] *= A_[j];
      }
      if (f1 == 2) break;   // consumed an inclusive prefix -> carry complete
      tk -= NS;
    }
  }
  // publish inclusive prefix (flag 2) BEFORE pass B to unblock successors
  #pragma unroll
  for (int j=0;j<4;j++){
    float PA = Ap[j]*accA[j];
    float PB = fmaf(Ap[j], accB[j], Bc[j]);
    __hip_atomic_store(prefA+base+j, PA, __ATOMIC_RELAXED, SCOPE);
    __hip_atomic_store(prefB+base+j, PB, __ATOMIC_RELAXED, SCOPE);
  }
  __threadfence();
  __syncthreads();
  if (threadIdx.x == 0)
    __hip_atomic_store(flags+tile, 2, __ATOMIC_RELEASE, SCOPE);

  // ---- pass B: recompute with carry-in, write hs/ys non-temporal ----
  float4 wcv = *(const float4*)(WC + n4*4);
  float4 bcv = *(const float4*)(bC + n4*4);
  float wc[4] = {wcv.x,wcv.y,wcv.z,wcv.w};
  float bc[4] = {bcv.x,bcv.y,bcv.z,bcv.w};
  float h[4]  = {accB[0],accB[1],accB[2],accB[3]};
  #pragma unroll 2
  for (int i=0;i<LC;i++){
    int l = l0+i;
    float x  = xs[(size_t)l*Dr + d];
    float dl = softplus_fast(dp + z[l]);
    float x2 = x*x;
    float y = 0.f;
    #pragma unroll
    for (int j=0;j<4;j++){
      float Ab = exp2_hw(dl*ad2[j]);
      float Bx = (Ab-1.f)*fmaf(x2, p[j], x*q[j]);
      h[j] = fmaf(Ab, h[j], Bx);
      y = fmaf(h[j], fmaf(x, wc[j], bc[j]), y);
    }
    f32x4 hv = {h[0],h[1],h[2],h[3]};
    __builtin_nontemporal_store(hv, (f32x4*)(hs + (size_t)l*DN + d*Nr + n4*4));
    y += __shfl_xor(y, 1, 64);
    y += __shfl_xor(y, 2, 64);
    if (n4 == 0) __builtin_nontemporal_store(y, ys + (size_t)l*Dr + d);
  }
}

extern "C" void kernel_launch(void* const* d_in, const int* in_sizes, int n_in,
                              void* d_out, int out_size, void* d_ws, size_t ws_size,
                              hipStream_t stream) {
  const float* xs     = (const float*)d_in[0];
  const float* WB     = (const float*)d_in[1];
  const float* bB     = (const float*)d_in[2];
  const float* WC     = (const float*)d_in[3];
  const float* bC     = (const float*)d_in[4];
  const float* WD     = (const float*)d_in[5];
  const float* bD     = (const float*)d_in[6];
  const float* lnA    = (const float*)d_in[7];
  const float* dparam = (const float*)d_in[8];

  float* ys = (float*)d_out;
  float* hs = ys + (size_t)Lr*Dr;

  const size_t TPB = (size_t)NT*CPB;         // 1M floats = 4 MB per array
  float* z     = (float*)d_ws;               // Lr floats
  float* aggA  = z + Lr;
  float* aggB  = aggA + TPB;
  float* prefA = aggB + TPB;
  float* prefB = prefA + TPB;
  int*   flags = (int*)(prefB + TPB);        // NT ints
  int*   ticket= flags + NT;                 // 1 int   (total ~16.8 MB)

  k_rowdot<<<Lr, 256, 0, stream>>>(xs, WD, bD, z, flags);
  k_fused<<<NT, 256, 0, stream>>>(xs, WB, bB, WC, bC, lnA, dparam, z,
                                  aggA, aggB, prefA, prefB, flags, ticket, ys, hs);
}

// Round 8
// 252.614 us; speedup vs baseline: 1.7232x; 1.7232x over previous
//
#include <hip/hip_runtime.h>

#define Lr 2048
#define Dr 1024
#define Nr 16
#define Gc 64           // chunks along L
#define LC 32           // Lr/Gc
#define NS 16           // d-slices (Dr/64)
#define NTILE 1024      // Gc*NS
#define NB 512          // fused grid: 2 blocks/CU, co-residency guaranteed
#define DN (Dr*Nr)      // 16384
#define GDN (Gc*DN)

#define LOG2E 1.442695041f
#define LN2   0.69314718056f
#define SCOPE __HIP_MEMORY_SCOPE_AGENT

typedef float f32x4 __attribute__((ext_vector_type(4)));

__device__ __forceinline__ float exp2_hw(float x){ return __builtin_amdgcn_exp2f(x); }
__device__ __forceinline__ float log2_hw(float x){ return __builtin_amdgcn_logf(x); }
__device__ __forceinline__ float exp_hw(float x) { return exp2_hw(x*LOG2E); }
__device__ __forceinline__ float softplus_fast(float x){
  float t = exp2_hw(-LOG2E*fabsf(x));
  return fmaxf(x, 0.f) + LN2*log2_hw(1.f + t);
}

// Full-grid arrive-and-wait barrier. Counter bar[slot] is zeroed by k_rowdot
// each launch (stream-ordered before k_fused). Counter only increments during
// the kernel, so "wait until == NB" is deterministic and race-free.
__device__ __forceinline__ void gridbar(int* bar, int slot){
  __threadfence();                 // make this block's stores agent-visible
  __syncthreads();
  if (threadIdx.x == 0){
    int prev = __hip_atomic_fetch_add(bar+slot, 1, __ATOMIC_ACQ_REL, SCOPE);
    if (prev != NB-1){
      int v;
      do {
        __builtin_amdgcn_s_sleep(8);
        v = __hip_atomic_load(bar+slot, __ATOMIC_ACQUIRE, SCOPE);
      } while (v < NB);
    }
  }
  __syncthreads();
}

// z[l] = dot(xs[l,:], WD) + bD; block 0 also zeroes the barrier counters.
__global__ void k_rowdot(const float* __restrict__ xs, const float* __restrict__ WD,
                         const float* __restrict__ bD, float* __restrict__ z,
                         int* __restrict__ bar){
  if (blockIdx.x == 0 && threadIdx.x < 4) bar[threadIdx.x] = 0;
  int l = blockIdx.x;
  const float4* row = (const float4*)(xs + (size_t)l*Dr);
  const float4* w4  = (const float4*)WD;
  int i = threadIdx.x;           // Dr/4 == 256 == blockDim
  float4 a = row[i], b = w4[i];
  float s = fmaf(a.x,b.x, fmaf(a.y,b.y, fmaf(a.z,b.z, a.w*b.w)));
  #pragma unroll
  for (int off = 32; off > 0; off >>= 1) s += __shfl_down(s, off, 64);
  __shared__ float red[4];
  int wid = threadIdx.x >> 6, lane = threadIdx.x & 63;
  if (lane == 0) red[wid] = s;
  __syncthreads();
  if (threadIdx.x == 0) z[l] = red[0] + red[1] + red[2] + red[3] + bD[0];
}

// Fused: {phase1 aggregates} bar0 {carry scan} bar1 {phase3 final+write}.
// Tile t = (g = t>>4, s = t&15); block b handles tiles b and b+NB.
// Thread: (d_local = tid>>2, n4 = tid&3) -> 4 chains.
__global__ __launch_bounds__(256, 2) void k_fused(
    const float* __restrict__ xs, const float* __restrict__ WB,
    const float* __restrict__ bB, const float* __restrict__ WC,
    const float* __restrict__ bC, const float* __restrict__ lnA,
    const float* __restrict__ dparam, const float* __restrict__ z,
    float* __restrict__ aggA, float* __restrict__ aggB,
    float* __restrict__ carry, int* __restrict__ bar,
    float* __restrict__ ys, float* __restrict__ hs){
  const int bid = blockIdx.x;
  const int n4 = threadIdx.x & 3, d_local = threadIdx.x >> 2;

  // ---------- phase 1: chunk aggregates for 2 tiles ----------
  for (int half = 0; half < 2; half++){
    const int tile = bid + half*NB;
    const int g = tile >> 4, s = tile & (NS-1);
    const int d = s*64 + d_local;
    float4 la = *(const float4*)(lnA + d*Nr + n4*4);
    float4 wb = *(const float4*)(WB + n4*4);
    float4 bb = *(const float4*)(bB + n4*4);
    float lav[4] = {la.x,la.y,la.z,la.w};
    float wbv[4] = {wb.x,wb.y,wb.z,wb.w};
    float bbv[4] = {bb.x,bb.y,bb.z,bb.w};
    float ad2[4], p[4], q[4];
    #pragma unroll
    for (int j=0;j<4;j++){
      float a = -exp_hw(lav[j]);
      ad2[j] = a*LOG2E;
      float ia = 1.f/a;
      p[j] = wbv[j]*ia; q[j] = bbv[j]*ia;
    }
    const float dp = dparam[d];
    const int l0 = g*LC;
    float Ap[4] = {1.f,1.f,1.f,1.f}, Bc[4] = {0.f,0.f,0.f,0.f};
    #pragma unroll 2
    for (int i=0;i<LC;i++){
      int l = l0+i;
      float x  = xs[(size_t)l*Dr + d];
      float dl = softplus_fast(dp + z[l]);
      float x2 = x*x;
      #pragma unroll
      for (int j=0;j<4;j++){
        float Ab = exp2_hw(dl*ad2[j]);
        float Bx = (Ab-1.f)*fmaf(x2, p[j], x*q[j]);
        Ap[j] *= Ab;
        Bc[j] = fmaf(Ab, Bc[j], Bx);
      }
    }
    *(float4*)(aggA + (size_t)g*DN + d*Nr + n4*4) = make_float4(Ap[0],Ap[1],Ap[2],Ap[3]);
    *(float4*)(aggB + (size_t)g*DN + d*Nr + n4*4) = make_float4(Bc[0],Bc[1],Bc[2],Bc[3]);
  }

  gridbar(bar, 0);

  // ---------- carry: blocks 0..63 scan 64 chunks per chain ----------
  if (bid < DN/256){
    const int t = bid*256 + threadIdx.x;   // chain id = d*Nr+n
    float h = 0.f;
    for (int g0 = 0; g0 < Gc; g0 += 8){
      float A_[8], B_[8];
      #pragma unroll
      for (int k=0;k<8;k++){
        A_[k] = aggA[(size_t)(g0+k)*DN + t];
        B_[k] = aggB[(size_t)(g0+k)*DN + t];
      }
      #pragma unroll
      for (int k=0;k<8;k++){
        carry[(size_t)(g0+k)*DN + t] = h;
        h = fmaf(A_[k], h, B_[k]);
      }
    }
  }

  gridbar(bar, 1);

  // ---------- phase 3: recompute with carry-in, write hs/ys ----------
  for (int half = 0; half < 2; half++){
    const int tile = bid + half*NB;
    const int g = tile >> 4, s = tile & (NS-1);
    const int d = s*64 + d_local;
    float4 la = *(const float4*)(lnA + d*Nr + n4*4);
    float4 wb = *(const float4*)(WB + n4*4);
    float4 bb = *(const float4*)(bB + n4*4);
    float4 wcv= *(const float4*)(WC + n4*4);
    float4 bcv= *(const float4*)(bC + n4*4);
    float4 h0 = *(const float4*)(carry + (size_t)g*DN + d*Nr + n4*4);
    float lav[4] = {la.x,la.y,la.z,la.w};
    float wbv[4] = {wb.x,wb.y,wb.z,wb.w};
    float bbv[4] = {bb.x,bb.y,bb.z,bb.w};
    float wc[4]  = {wcv.x,wcv.y,wcv.z,wcv.w};
    float bc[4]  = {bcv.x,bcv.y,bcv.z,bcv.w};
    float h[4]   = {h0.x,h0.y,h0.z,h0.w};
    float ad2[4], p[4], q[4];
    #pragma unroll
    for (int j=0;j<4;j++){
      float a = -exp_hw(lav[j]);
      ad2[j] = a*LOG2E;
      float ia = 1.f/a;
      p[j] = wbv[j]*ia; q[j] = bbv[j]*ia;
    }
    const float dp = dparam[d];
    const int l0 = g*LC;
    #pragma unroll 2
    for (int i=0;i<LC;i++){
      int l = l0+i;
      float x  = xs[(size_t)l*Dr + d];
      float dl = softplus_fast(dp + z[l]);
      float x2 = x*x;
      float y = 0.f;
      #pragma unroll
      for (int j=0;j<4;j++){
        float Ab = exp2_hw(dl*ad2[j]);
        float Bx = (Ab-1.f)*fmaf(x2, p[j], x*q[j]);
        h[j] = fmaf(Ab, h[j], Bx);
        y = fmaf(h[j], fmaf(x, wc[j], bc[j]), y);
      }
      f32x4 hv = {h[0],h[1],h[2],h[3]};
      __builtin_nontemporal_store(hv, (f32x4*)(hs + (size_t)l*DN + d*Nr + n4*4));
      y += __shfl_xor(y, 1, 64);
      y += __shfl_xor(y, 2, 64);
      if (n4 == 0) __builtin_nontemporal_store(y, ys + (size_t)l*Dr + d);
    }
  }
}

extern "C" void kernel_launch(void* const* d_in, const int* in_sizes, int n_in,
                              void* d_out, int out_size, void* d_ws, size_t ws_size,
                              hipStream_t stream) {
  const float* xs     = (const float*)d_in[0];
  const float* WB     = (const float*)d_in[1];
  const float* bB     = (const float*)d_in[2];
  const float* WC     = (const float*)d_in[3];
  const float* bC     = (const float*)d_in[4];
  const float* WD     = (const float*)d_in[5];
  const float* bD     = (const float*)d_in[6];
  const float* lnA    = (const float*)d_in[7];
  const float* dparam = (const float*)d_in[8];

  float* ys = (float*)d_out;
  float* hs = ys + (size_t)Lr*Dr;

  float* z     = (float*)d_ws;               // Lr floats
  float* aggA  = z + Lr;                     // GDN
  float* aggB  = aggA + GDN;                 // GDN
  float* carry = aggB + GDN;                 // GDN
  int*   bar   = (int*)(carry + GDN);        // 4 ints  (total ~12.6 MB)

  k_rowdot<<<Lr, 256, 0, stream>>>(xs, WD, bD, z, bar);
  k_fused<<<NB, 256, 0, stream>>>(xs, WB, bB, WC, bC, lnA, dparam, z,
                                  aggA, aggB, carry, bar, ys, hs);
}

// Round 9
// 111.800 us; speedup vs baseline: 3.8936x; 2.2595x over previous
//
#include <hip/hip_runtime.h>

#define Lr 2048
#define Dr 1024
#define Nr 16
#define Gc 64           // chunks along L
#define LC 32           // Lr/Gc
#define NS 16           // d-slices (Dr/64)
#define NTILE 1024      // Gc*NS
#define DN (Dr*Nr)      // 16384
#define GDN (Gc*DN)

#define LOG2E 1.442695041f
#define LN2   0.69314718056f

typedef float f32x4 __attribute__((ext_vector_type(4)));

__device__ __forceinline__ float exp2_hw(float x){ return __builtin_amdgcn_exp2f(x); }
__device__ __forceinline__ float log2_hw(float x){ return __builtin_amdgcn_logf(x); }
__device__ __forceinline__ float exp_hw(float x) { return exp2_hw(x*LOG2E); }
__device__ __forceinline__ float softplus_fast(float x){
  float t = exp2_hw(-LOG2E*fabsf(x));
  return fmaxf(x, 0.f) + LN2*log2_hw(1.f + t);
}

// Per-block z computation for this chunk's 32 rows: 8 threads per row,
// 128 elems each (32 x float4), shfl-reduce over the 8 lanes -> LDS.
// Redundant across the 16 d-slices (cheap: 128KB L2-hot + ~4K FMA/block);
// removes the separate rowdot kernel and the z global round-trip.
__device__ __forceinline__ void compute_z_chunk(
    const float* __restrict__ xs, const float* __restrict__ WD,
    const float* __restrict__ bD, int l0, float* zloc){
  int l_i = threadIdx.x >> 3;      // 0..31
  int seg = threadIdx.x & 7;       // 0..7
  const float4* row = (const float4*)(xs + (size_t)(l0+l_i)*Dr) + seg*32;
  const float4* w4  = (const float4*)WD + seg*32;
  float s = 0.f;
  #pragma unroll
  for (int k=0;k<32;k++){
    float4 a = row[k], w = w4[k];
    s = fmaf(a.x,w.x, fmaf(a.y,w.y, fmaf(a.z,w.z, fmaf(a.w,w.w, s))));
  }
  s += __shfl_xor(s, 1, 64);
  s += __shfl_xor(s, 2, 64);
  s += __shfl_xor(s, 4, 64);
  if (seg == 0) zloc[l_i] = s + bD[0];
  __syncthreads();
}

// Phase 1: tile (g = bid>>4, s = bid&15); thread (d_local = tid>>2, n4 = tid&3)
// owns 4 chains; computes chunk aggregates (prod A, local scan-B).
__global__ __launch_bounds__(256) void k_phase1(
    const float* __restrict__ xs, const float* __restrict__ WB,
    const float* __restrict__ bB, const float* __restrict__ lnA,
    const float* __restrict__ dparam, const float* __restrict__ WD,
    const float* __restrict__ bD,
    float* __restrict__ aggA, float* __restrict__ aggB){
  const int g = blockIdx.x >> 4, s = blockIdx.x & (NS-1);
  const int l0 = g*LC;
  __shared__ float zloc[LC];
  compute_z_chunk(xs, WD, bD, l0, zloc);

  const int n4 = threadIdx.x & 3, d_local = threadIdx.x >> 2;
  const int d = s*64 + d_local;
  float4 la = *(const float4*)(lnA + d*Nr + n4*4);
  float4 wb = *(const float4*)(WB + n4*4);
  float4 bb = *(const float4*)(bB + n4*4);
  float lav[4] = {la.x,la.y,la.z,la.w};
  float wbv[4] = {wb.x,wb.y,wb.z,wb.w};
  float bbv[4] = {bb.x,bb.y,bb.z,bb.w};
  float ad2[4], p[4], q[4];
  #pragma unroll
  for (int j=0;j<4;j++){
    float a = -exp_hw(lav[j]);
    ad2[j] = a*LOG2E;
    float ia = 1.f/a;
    p[j] = wbv[j]*ia; q[j] = bbv[j]*ia;
  }
  const float dp = dparam[d];
  float Ap[4] = {1.f,1.f,1.f,1.f}, Bc[4] = {0.f,0.f,0.f,0.f};
  #pragma unroll 2
  for (int i=0;i<LC;i++){
    int l = l0+i;
    float x  = xs[(size_t)l*Dr + d];
    float dl = softplus_fast(dp + zloc[i]);
    float x2 = x*x;
    #pragma unroll
    for (int j=0;j<4;j++){
      float Ab = exp2_hw(dl*ad2[j]);
      float Bx = (Ab-1.f)*fmaf(x2, p[j], x*q[j]);
      Ap[j] *= Ab;
      Bc[j] = fmaf(Ab, Bc[j], Bx);
    }
  }
  *(float4*)(aggA + (size_t)g*DN + d*Nr + n4*4) = make_float4(Ap[0],Ap[1],Ap[2],Ap[3]);
  *(float4*)(aggB + (size_t)g*DN + d*Nr + n4*4) = make_float4(Bc[0],Bc[1],Bc[2],Bc[3]);
}

// Phase 2: per-chain serial scan over 64 chunks; 256 blocks x 64 threads,
// unroll 16 for load batching.
__global__ __launch_bounds__(64) void k_carry(
    const float* __restrict__ aggA, const float* __restrict__ aggB,
    float* __restrict__ carry){
  const int t = blockIdx.x*64 + threadIdx.x;   // chain id = d*Nr+n
  float h = 0.f;
  for (int g0 = 0; g0 < Gc; g0 += 16){
    float A_[16], B_[16];
    #pragma unroll
    for (int k=0;k<16;k++){
      A_[k] = aggA[(size_t)(g0+k)*DN + t];
      B_[k] = aggB[(size_t)(g0+k)*DN + t];
    }
    #pragma unroll
    for (int k=0;k<16;k++){
      carry[(size_t)(g0+k)*DN + t] = h;
      h = fmaf(A_[k], h, B_[k]);
    }
  }
}

// Phase 3: recompute with carry-in, write hs/ys (non-temporal).
__global__ __launch_bounds__(256) void k_phase3(
    const float* __restrict__ xs, const float* __restrict__ WB,
    const float* __restrict__ bB, const float* __restrict__ WC,
    const float* __restrict__ bC, const float* __restrict__ lnA,
    const float* __restrict__ dparam, const float* __restrict__ WD,
    const float* __restrict__ bD, const float* __restrict__ carry,
    float* __restrict__ ys, float* __restrict__ hs){
  const int g = blockIdx.x >> 4, s = blockIdx.x & (NS-1);
  const int l0 = g*LC;
  __shared__ float zloc[LC];
  compute_z_chunk(xs, WD, bD, l0, zloc);

  const int n4 = threadIdx.x & 3, d_local = threadIdx.x >> 2;
  const int d = s*64 + d_local;
  float4 la = *(const float4*)(lnA + d*Nr + n4*4);
  float4 wb = *(const float4*)(WB + n4*4);
  float4 bb = *(const float4*)(bB + n4*4);
  float4 wcv= *(const float4*)(WC + n4*4);
  float4 bcv= *(const float4*)(bC + n4*4);
  float4 h0 = *(const float4*)(carry + (size_t)g*DN + d*Nr + n4*4);
  float lav[4] = {la.x,la.y,la.z,la.w};
  float wbv[4] = {wb.x,wb.y,wb.z,wb.w};
  float bbv[4] = {bb.x,bb.y,bb.z,bb.w};
  float wc[4]  = {wcv.x,wcv.y,wcv.z,wcv.w};
  float bc[4]  = {bcv.x,bcv.y,bcv.z,bcv.w};
  float h[4]   = {h0.x,h0.y,h0.z,h0.w};
  float ad2[4], p[4], q[4];
  #pragma unroll
  for (int j=0;j<4;j++){
    float a = -exp_hw(lav[j]);
    ad2[j] = a*LOG2E;
    float ia = 1.f/a;
    p[j] = wbv[j]*ia; q[j] = bbv[j]*ia;
  }
  const float dp = dparam[d];
  #pragma unroll 2
  for (int i=0;i<LC;i++){
    int l = l0+i;
    float x  = xs[(size_t)l*Dr + d];
    float dl = softplus_fast(dp + zloc[i]);
    float x2 = x*x;
    float y = 0.f;
    #pragma unroll
    for (int j=0;j<4;j++){
      float Ab = exp2_hw(dl*ad2[j]);
      float Bx = (Ab-1.f)*fmaf(x2, p[j], x*q[j]);
      h[j] = fmaf(Ab, h[j], Bx);
      y = fmaf(h[j], fmaf(x, wc[j], bc[j]), y);
    }
    f32x4 hv = {h[0],h[1],h[2],h[3]};
    __builtin_nontemporal_store(hv, (f32x4*)(hs + (size_t)l*DN + d*Nr + n4*4));
    y += __shfl_xor(y, 1, 64);
    y += __shfl_xor(y, 2, 64);
    if (n4 == 0) __builtin_nontemporal_store(y, ys + (size_t)l*Dr + d);
  }
}

extern "C" void kernel_launch(void* const* d_in, const int* in_sizes, int n_in,
                              void* d_out, int out_size, void* d_ws, size_t ws_size,
                              hipStream_t stream) {
  const float* xs     = (const float*)d_in[0];
  const float* WB     = (const float*)d_in[1];
  const float* bB     = (const float*)d_in[2];
  const float* WC     = (const float*)d_in[3];
  const float* bC     = (const float*)d_in[4];
  const float* WD     = (const float*)d_in[5];
  const float* bD     = (const float*)d_in[6];
  const float* lnA    = (const float*)d_in[7];
  const float* dparam = (const float*)d_in[8];

  float* ys = (float*)d_out;
  float* hs = ys + (size_t)Lr*Dr;

  float* aggA  = (float*)d_ws;               // GDN
  float* aggB  = aggA + GDN;                 // GDN
  float* carry = aggB + GDN;                 // GDN  (total 12 MB)

  k_phase1<<<NTILE, 256, 0, stream>>>(xs, WB, bB, lnA, dparam, WD, bD, aggA, aggB);
  k_carry<<<DN/64, 64, 0, stream>>>(aggA, aggB, carry);
  k_phase3<<<NTILE, 256, 0, stream>>>(xs, WB, bB, WC, bC, lnA, dparam, WD, bD,
                                      carry, ys, hs);
}

// Round 10
// 66.677 us; speedup vs baseline: 6.5286x; 1.6767x over previous
//
#include <hip/hip_runtime.h>

#define Lr 2048
#define Dr 1024
#define Nr 16
#define Gc 32           // chunks along L
#define LC (Lr/Gc)      // 64
#define DN (Dr*Nr)      // 16384
#define GDN (Gc*DN)

#define LOG2E 1.442695041f
#define LN2   0.69314718056f

typedef float f32x4 __attribute__((ext_vector_type(4)));

__device__ __forceinline__ float exp2_hw(float x){ return __builtin_amdgcn_exp2f(x); }
__device__ __forceinline__ float log2_hw(float x){ return __builtin_amdgcn_logf(x); }
__device__ __forceinline__ float exp_hw(float x) { return exp2_hw(x*LOG2E); }
__device__ __forceinline__ float softplus_fast(float x){
  float t = exp2_hw(-LOG2E*fabsf(x));
  return fmaxf(x, 0.f) + LN2*log2_hw(1.f + t);
}

// z[l] = dot(xs[l,:], WD) + bD  (8 KB output; keep as its own tiny kernel —
// folding it into the phase kernels costs 16x redundant xs reads, measured
// +50us in R9)
__global__ void k_rowdot(const float* __restrict__ xs, const float* __restrict__ WD,
                         const float* __restrict__ bD, float* __restrict__ z){
  int l = blockIdx.x;
  const float4* row = (const float4*)(xs + (size_t)l*Dr);
  const float4* w4  = (const float4*)WD;
  int i = threadIdx.x;           // Dr/4 == 256 == blockDim
  float4 a = row[i], b = w4[i];
  float s = fmaf(a.x,b.x, fmaf(a.y,b.y, fmaf(a.z,b.z, a.w*b.w)));
  #pragma unroll
  for (int off = 32; off > 0; off >>= 1) s += __shfl_down(s, off, 64);
  __shared__ float red[4];
  int wid = threadIdx.x >> 6, lane = threadIdx.x & 63;
  if (lane == 0) red[wid] = s;
  __syncthreads();
  if (threadIdx.x == 0) z[l] = red[0] + red[1] + red[2] + red[3] + bD[0];
}

// Phase 1: thread per (chunk g, channel d, n-quad n4); 4 chains per thread.
__global__ __launch_bounds__(256) void k_phase1(
    const float* __restrict__ xs, const float* __restrict__ WB,
    const float* __restrict__ bB,
    const float* __restrict__ lnA, const float* __restrict__ dparam,
    const float* __restrict__ z,
    float* __restrict__ aggA, float* __restrict__ aggB){
  int t  = blockIdx.x*256 + threadIdx.x;
  int g  = t >> 12;             // Dr*4 = 4096 threads per chunk
  int r  = t & 4095;
  int d  = r >> 2;
  int n4 = r & 3;
  float4 la = *(const float4*)(lnA + d*Nr + n4*4);
  float4 wb = *(const float4*)(WB  + n4*4);
  float4 bb = *(const float4*)(bB  + n4*4);
  float lav[4] = {la.x,la.y,la.z,la.w};
  float wbv[4] = {wb.x,wb.y,wb.z,wb.w};
  float bbv[4] = {bb.x,bb.y,bb.z,bb.w};
  float ad2[4], p[4], q[4], Ap[4], Bc[4];
  #pragma unroll
  for (int j=0;j<4;j++){
    float a = -exp_hw(lav[j]);
    ad2[j] = a*LOG2E;                 // Adiag * log2(e) for exp2
    float ia = 1.f/a;
    p[j]=wbv[j]*ia; q[j]=bbv[j]*ia; Ap[j]=1.f; Bc[j]=0.f;
  }
  float dp = dparam[d];
  int l0 = g*LC;
  #pragma unroll 2
  for (int i=0;i<LC;i++){
    int l = l0+i;
    float x  = xs[(size_t)l*Dr + d];
    float dl = softplus_fast(dp + z[l]);
    float x2 = x*x;
    #pragma unroll
    for (int j=0;j<4;j++){
      float Ab = exp2_hw(dl*ad2[j]);
      float Bx = (Ab-1.f)*fmaf(x2, p[j], x*q[j]);
      Ap[j] *= Ab;
      Bc[j] = fmaf(Ab, Bc[j], Bx);
    }
  }
  *(float4*)(aggA + (size_t)g*DN + d*Nr + n4*4) = make_float4(Ap[0],Ap[1],Ap[2],Ap[3]);
  *(float4*)(aggB + (size_t)g*DN + d*Nr + n4*4) = make_float4(Bc[0],Bc[1],Bc[2],Bc[3]);
}

// Phase 2: per-chain serial scan over 32 chunks; 256 blocks x 64 threads,
// unroll 16 for load batching (32 loads in flight).
__global__ __launch_bounds__(64) void k_carry(
    const float* __restrict__ aggA, const float* __restrict__ aggB,
    float* __restrict__ carry){
  const int t = blockIdx.x*64 + threadIdx.x;   // chain id = d*Nr+n
  float h = 0.f;
  for (int g0 = 0; g0 < Gc; g0 += 16){
    float A_[16], B_[16];
    #pragma unroll
    for (int k=0;k<16;k++){
      A_[k] = aggA[(size_t)(g0+k)*DN + t];
      B_[k] = aggB[(size_t)(g0+k)*DN + t];
    }
    #pragma unroll
    for (int k=0;k<16;k++){
      carry[(size_t)(g0+k)*DN + t] = h;
      h = fmaf(A_[k], h, B_[k]);
    }
  }
}

// Phase 3: recompute elementwise with carry-in, write hs and ys (non-temporal).
__global__ __launch_bounds__(256) void k_phase3(
    const float* __restrict__ xs, const float* __restrict__ WB,
    const float* __restrict__ bB, const float* __restrict__ WC,
    const float* __restrict__ bC,
    const float* __restrict__ lnA, const float* __restrict__ dparam,
    const float* __restrict__ z, const float* __restrict__ carry,
    float* __restrict__ ys, float* __restrict__ hs){
  int t  = blockIdx.x*256 + threadIdx.x;
  int g  = t >> 12;
  int r  = t & 4095;
  int d  = r >> 2;
  int n4 = r & 3;
  float4 la = *(const float4*)(lnA + d*Nr + n4*4);
  float4 wb = *(const float4*)(WB  + n4*4);
  float4 bb = *(const float4*)(bB  + n4*4);
  float4 wcv= *(const float4*)(WC  + n4*4);
  float4 bcv= *(const float4*)(bC  + n4*4);
  float4 h0 = *(const float4*)(carry + (size_t)g*DN + d*Nr + n4*4);
  float lav[4] = {la.x,la.y,la.z,la.w};
  float wbv[4] = {wb.x,wb.y,wb.z,wb.w};
  float bbv[4] = {bb.x,bb.y,bb.z,bb.w};
  float wc[4]  = {wcv.x,wcv.y,wcv.z,wcv.w};
  float bc[4]  = {bcv.x,bcv.y,bcv.z,bcv.w};
  float h[4]   = {h0.x,h0.y,h0.z,h0.w};
  float ad2[4], p[4], q[4];
  #pragma unroll
  for (int j=0;j<4;j++){
    float a = -exp_hw(lav[j]);
    ad2[j] = a*LOG2E;
    float ia = 1.f/a;
    p[j]=wbv[j]*ia; q[j]=bbv[j]*ia;
  }
  float dp = dparam[d];
  int l0 = g*LC;
  #pragma unroll 2
  for (int i=0;i<LC;i++){
    int l = l0+i;
    float x  = xs[(size_t)l*Dr + d];
    float dl = softplus_fast(dp + z[l]);
    float x2 = x*x;
    float y = 0.f;
    #pragma unroll
    for (int j=0;j<4;j++){
      float Ab = exp2_hw(dl*ad2[j]);
      float Bx = (Ab-1.f)*fmaf(x2, p[j], x*q[j]);
      h[j] = fmaf(Ab, h[j], Bx);
      y = fmaf(h[j], fmaf(x, wc[j], bc[j]), y);
    }
    f32x4 hv = {h[0],h[1],h[2],h[3]};
    __builtin_nontemporal_store(hv, (f32x4*)(hs + (size_t)l*DN + d*Nr + n4*4));
    // reduce y over the 4 n-lanes sharing this d (lanes 4k..4k+3)
    y += __shfl_xor(y, 1, 64);
    y += __shfl_xor(y, 2, 64);
    if (n4 == 0) __builtin_nontemporal_store(y, &ys[(size_t)l*Dr + d]);
  }
}

extern "C" void kernel_launch(void* const* d_in, const int* in_sizes, int n_in,
                              void* d_out, int out_size, void* d_ws, size_t ws_size,
                              hipStream_t stream) {
  const float* xs     = (const float*)d_in[0];
  const float* WB     = (const float*)d_in[1];
  const float* bB     = (const float*)d_in[2];
  const float* WC     = (const float*)d_in[3];
  const float* bC     = (const float*)d_in[4];
  const float* WD     = (const float*)d_in[5];
  const float* bD     = (const float*)d_in[6];
  const float* lnA    = (const float*)d_in[7];
  const float* dparam = (const float*)d_in[8];

  float* ys = (float*)d_out;
  float* hs = ys + (size_t)Lr*Dr;

  float* z     = (float*)d_ws;          // Lr
  float* aggA  = z + Lr;                // GDN
  float* aggB  = aggA + GDN;            // GDN
  float* carry = aggB + GDN;            // GDN  (total ~6.3 MB)

  k_rowdot<<<Lr, 256, 0, stream>>>(xs, WD, bD, z);
  k_phase1<<<(Gc*Dr*4)/256, 256, 0, stream>>>(xs, WB, bB, lnA, dparam, z, aggA, aggB);
  k_carry<<<DN/64, 64, 0, stream>>>(aggA, aggB, carry);
  k_phase3<<<(Gc*Dr*4)/256, 256, 0, stream>>>(xs, WB, bB, WC, bC, lnA, dparam, z, carry, ys, hs);
}